// Round 13
// baseline (719.932 us; speedup 1.0000x reference)
//
#include <hip/hip_runtime.h>

#define NN 50000
#define EE 800000
#define FIN 16
#define EDIM 4
#define EMB 32
#define NH 4
#define HC 128          // EMB*NH
#define NL 2
#define DENSE 128
#define QNPB 50         // nodes per qkvs/ftq/head block (50000 = 1000 * 50)
#define SBLK 49         // scan blocks: ceil(50000/1024)

typedef unsigned int uint;

// unpack two packed fp16 -> float2
__device__ __forceinline__ float2 h2f2(uint u) {
    union { uint u; _Float16 h[2]; } c; c.u = u;
    return make_float2((float)c.h[0], (float)c.h[1]);
}
__device__ __forceinline__ uint pkh2(float a, float b) {
    union { uint u; _Float16 h[2]; } c;
    c.h[0] = (_Float16)a; c.h[1] = (_Float16)b; return c.u;
}

// ---------------- CSR build ----------------
__global__ void hist_kernel(const int* __restrict__ dst, int* __restrict__ counts) {
    int e = blockIdx.x * blockDim.x + threadIdx.x;
    if (e < EE) atomicAdd(&counts[dst[e]], 1);
}

__global__ __launch_bounds__(1024) void scan1_kernel(const int* __restrict__ cursor,
                                                     int* __restrict__ row_ptr,
                                                     int* __restrict__ bsum) {
    __shared__ int wsum[16];
    __shared__ int wpre[17];
    int tid = threadIdx.x, lane = tid & 63, wid = tid >> 6;
    int i = blockIdx.x * 1024 + tid;
    int v = (i < NN) ? cursor[i] : 0;
    int incl = v;
    #pragma unroll
    for (int off = 1; off < 64; off <<= 1) {
        int t = __shfl_up(incl, off, 64);
        if (lane >= off) incl += t;
    }
    if (lane == 63) wsum[wid] = incl;
    __syncthreads();
    if (tid == 0) {
        int acc = 0;
        #pragma unroll
        for (int w = 0; w < 16; ++w) { wpre[w] = acc; acc += wsum[w]; }
        wpre[16] = acc;
    }
    __syncthreads();
    if (i < NN) row_ptr[i] = wpre[wid] + incl - v;
    if (tid == 0) bsum[blockIdx.x] = wpre[16];
}

__global__ void scan2_kernel(int* __restrict__ bsum, int* __restrict__ row_ptr) {
    int t = threadIdx.x;                               // 64 threads
    int v = (t < SBLK) ? bsum[t] : 0;
    int incl = v;
    #pragma unroll
    for (int off = 1; off < 64; off <<= 1) {
        int u = __shfl_up(incl, off, 64);
        if (t >= off) incl += u;
    }
    if (t < SBLK) bsum[t] = incl - v;
    if (t == 63) row_ptr[NN] = incl;
}

__global__ __launch_bounds__(1024) void scan3_kernel(int* __restrict__ row_ptr,
                                                     int* __restrict__ cursor,
                                                     const int* __restrict__ bsum) {
    int i = blockIdx.x * 1024 + threadIdx.x;
    if (i >= NN) return;
    int r = row_ptr[i] + bsum[blockIdx.x];
    row_ptr[i] = r;
    cursor[i] = r;
}

__global__ void scatter_kernel(const int* __restrict__ src, const int* __restrict__ dst,
                               const float* __restrict__ ea, int* __restrict__ cursor,
                               int* __restrict__ ssrc, float4* __restrict__ sea) {
    int e = blockIdx.x * blockDim.x + threadIdx.x;
    if (e >= EE) return;
    int d = dst[e];
    int pos = atomicAdd(&cursor[d], 1);
    ssrc[pos] = src[e];
    sea[pos] = *reinterpret_cast<const float4*>(ea + (size_t)e * 4);
}

// ------- layer-0 projections: all 4 matrices per thread (1 h-read -> 4 dots) ---------
__global__ __launch_bounds__(512) void qkvs0_kernel(const float* __restrict__ x,
        const float* __restrict__ Wq, const float* __restrict__ bq,
        const float* __restrict__ Wk, const float* __restrict__ bk,
        const float* __restrict__ Wv, const float* __restrict__ bv,
        const float* __restrict__ Ws, const float* __restrict__ bs,
        float* __restrict__ Q, uint* __restrict__ kvu,
        float* __restrict__ Out) {
    __shared__ __align__(16) float hs[QNPB * FIN];
    int tid = threadIdx.x;
    int c = tid & 127, g = tid >> 7;
    float wq[FIN], wk[FIN], wv[FIN], wsk[FIN];
    #pragma unroll
    for (int f = 0; f < FIN; ++f) {
        wq[f] = Wq[f * HC + c]; wk[f] = Wk[f * HC + c];
        wv[f] = Wv[f * HC + c]; wsk[f] = Ws[f * HC + c];
    }
    float bq_ = bq[c], bk_ = bk[c], bv_ = bv[c], bs_ = bs[c];
    int node0 = blockIdx.x * QNPB;
    {
        const float4* src4 = (const float4*)(x + (size_t)node0 * FIN);
        float4* dst4 = (float4*)hs;
        for (int i = tid; i < QNPB * FIN / 4; i += 512) dst4[i] = src4[i];
    }
    __syncthreads();
    for (int k = g; k < QNPB; k += 4) {
        const float4* h4 = (const float4*)(hs + k * FIN);
        float sq = bq_, sk = bk_, sv = bv_, ss = bs_;
        #pragma unroll
        for (int f4 = 0; f4 < FIN / 4; ++f4) {
            float4 hv = h4[f4];
            sq += hv.x * wq[4*f4] + hv.y * wq[4*f4+1] + hv.z * wq[4*f4+2] + hv.w * wq[4*f4+3];
            sk += hv.x * wk[4*f4] + hv.y * wk[4*f4+1] + hv.z * wk[4*f4+2] + hv.w * wk[4*f4+3];
            sv += hv.x * wv[4*f4] + hv.y * wv[4*f4+1] + hv.z * wv[4*f4+2] + hv.w * wv[4*f4+3];
            ss += hv.x * wsk[4*f4] + hv.y * wsk[4*f4+1] + hv.z * wsk[4*f4+2] + hv.w * wsk[4*f4+3];
        }
        size_t n = node0 + k;
        Q[n * HC + c] = sq;
        kvu[n * 128 + c] = pkh2(sk, sv);
        Out[n * HC + c] = ss;
    }
}

// ---- fused transform + projections: reg-cached Wt (rotated reads) + merged QKVS -----
__global__ __launch_bounds__(512) void ftq_kernel(const float* __restrict__ Wt,
        const float* __restrict__ bt,
        const float* __restrict__ Wq, const float* __restrict__ bq,
        const float* __restrict__ Wk, const float* __restrict__ bk,
        const float* __restrict__ Wv, const float* __restrict__ bv,
        const float* __restrict__ Ws, const float* __restrict__ bs,
        float* __restrict__ Q, uint* __restrict__ kvu,
        float* __restrict__ Out) {
    __shared__ __align__(16) float os[QNPB * HC];   // 25.6 KB
    __shared__ __align__(16) float hs[QNPB * EMB];  // 6.4 KB
    int tid = threadIdx.x;
    int node0 = blockIdx.x * QNPB;
    int g = tid >> 7;                   // 4 node-groups (2 waves each)

    {   // float4 staging copy
        const float4* src4 = (const float4*)(Out + (size_t)node0 * HC);
        float4* dst4 = (float4*)os;
        for (int i = tid; i < QNPB * HC / 4; i += 512) dst4[i] = src4[i];
    }

    // stage T: h = relu(bt + Out @ Wt). thread (g, cT=(tid&127)>>2, seg=tid&3)
    int cT = (tid & 127) >> 2, seg = tid & 3;
    float wt[32];
    #pragma unroll
    for (int j = 0; j < 32; ++j) wt[j] = Wt[(seg * 32 + j) * EMB + cT];
    float btc = bt[cT];
    __syncthreads();
    for (int k = g; k < QNPB; k += 4) {
        float p = 0.f;
        const float4* r4 = (const float4*)(os + k * HC + seg * 32);
        #pragma unroll
        for (int jj = 0; jj < 8; ++jj) {
            int j4 = (seg * 2 + jj) & 7;        // rotate: break 4-way bank conflict
            float4 rv = r4[j4];
            p += rv.x * wt[4 * j4] + rv.y * wt[4 * j4 + 1]
               + rv.z * wt[4 * j4 + 2] + rv.w * wt[4 * j4 + 3];
        }
        p += __shfl_xor(p, 1, 64);      // seg pairs
        p += __shfl_xor(p, 2, 64);
        if (seg == 0) hs[k * EMB + cT] = fmaxf(p + btc, 0.f);
    }
    __syncthreads();

    // stage QKVS: all 4 matrices per thread — 1 h-read feeds 4 dot products
    int c = tid & 127;
    float wq[EMB], wk[EMB], wv[EMB], wsk[EMB];   // 128 VGPRs
    #pragma unroll
    for (int f = 0; f < EMB; ++f) {
        wq[f] = Wq[f * HC + c]; wk[f] = Wk[f * HC + c];
        wv[f] = Wv[f * HC + c]; wsk[f] = Ws[f * HC + c];
    }
    float bq_ = bq[c], bk_ = bk[c], bv_ = bv[c], bs_ = bs[c];
    for (int k = g; k < QNPB; k += 4) {
        const float4* h4 = (const float4*)(hs + k * EMB);
        float sq = bq_, sk = bk_, sv = bv_, ss = bs_;
        #pragma unroll
        for (int f4 = 0; f4 < EMB / 4; ++f4) {
            float4 hv = h4[f4];
            sq += hv.x * wq[4*f4] + hv.y * wq[4*f4+1] + hv.z * wq[4*f4+2] + hv.w * wq[4*f4+3];
            sk += hv.x * wk[4*f4] + hv.y * wk[4*f4+1] + hv.z * wk[4*f4+2] + hv.w * wk[4*f4+3];
            sv += hv.x * wv[4*f4] + hv.y * wv[4*f4+1] + hv.z * wv[4*f4+2] + hv.w * wv[4*f4+3];
            ss += hv.x * wsk[4*f4] + hv.y * wsk[4*f4+1] + hv.z * wsk[4*f4+2] + hv.w * wsk[4*f4+3];
        }
        size_t n = node0 + k;
        Q[n * HC + c] = sq;
        kvu[n * 128 + c] = pkh2(sk, sv);
        Out[n * HC + c] = ss;
    }
}

// ------- edge attention (round-9/11 version: 24 VGPR, occupancy-optimal) -------------
__global__ __launch_bounds__(256) void edge_attn_kernel(const int* __restrict__ row_ptr,
        const int* __restrict__ ssrc, const float4* __restrict__ sea,
        const float* __restrict__ We,
        const float* __restrict__ Q, const uint2* __restrict__ kvp,
        float2* __restrict__ Out) {
    int n = blockIdx.x * 4 + (threadIdx.x >> 6);   // grid*4 == NN exactly
    int lane = threadIdx.x & 63;
    int ch0 = 2 * lane, ch1 = 2 * lane + 1;
    float we0[4], we1[4];
    #pragma unroll
    for (int d = 0; d < 4; ++d) { we0[d] = We[d * HC + ch0]; we1[d] = We[d * HC + ch1]; }
    float2 q = ((const float2*)Q)[(size_t)n * 64 + lane];
    int start = row_ptr[n], end = row_ptr[n + 1];
    float z = 0.f, acc0 = 0.f, acc1 = 0.f;
    const float SC = 0.17677669529663687f;  // 1/sqrt(32)
    int i = start;
    for (; i + 1 < end; i += 2) {
        int sA = ssrc[i], sB = ssrc[i + 1];
        sA = sA < 0 ? 0 : (sA >= NN ? NN - 1 : sA);
        sB = sB < 0 ? 0 : (sB >= NN ? NN - 1 : sB);
        float4 eA = sea[i], eB = sea[i + 1];                     // wave-uniform
        uint2 kvA = kvp[(size_t)sA * 64 + lane];                 // k0,v0,k1,v1 fp16
        uint2 kvB = kvp[(size_t)sB * 64 + lane];
        float eA0 = eA.x * we0[0] + eA.y * we0[1] + eA.z * we0[2] + eA.w * we0[3];
        float eA1 = eA.x * we1[0] + eA.y * we1[1] + eA.z * we1[2] + eA.w * we1[3];
        float eB0 = eB.x * we0[0] + eB.y * we0[1] + eB.z * we0[2] + eB.w * we0[3];
        float eB1 = eB.x * we1[0] + eB.y * we1[1] + eB.z * we1[2] + eB.w * we1[3];
        float2 kvA0 = h2f2(kvA.x), kvA1 = h2f2(kvA.y);           // (k,v) ch0 / ch1
        float2 kvB0 = h2f2(kvB.x), kvB1 = h2f2(kvB.y);
        float pA = q.x * (kvA0.x + eA0) + q.y * (kvA1.x + eA1);
        float pB = q.x * (kvB0.x + eB0) + q.y * (kvB1.x + eB1);
        #pragma unroll
        for (int off = 1; off < 16; off <<= 1) {                 // 16-lane head groups
            pA += __shfl_xor(pA, off, 64);
            pB += __shfl_xor(pB, off, 64);
        }
        float xA = __expf(pA * SC), xB = __expf(pB * SC);
        z += xA + xB;
        acc0 += xA * (kvA0.y + eA0) + xB * (kvB0.y + eB0);
        acc1 += xA * (kvA1.y + eA1) + xB * (kvB1.y + eB1);
    }
    if (i < end) {
        int s = ssrc[i];
        s = s < 0 ? 0 : (s >= NN ? NN - 1 : s);
        float4 e = sea[i];
        uint2 kv = kvp[(size_t)s * 64 + lane];
        float e0 = e.x * we0[0] + e.y * we0[1] + e.z * we0[2] + e.w * we0[3];
        float e1 = e.x * we1[0] + e.y * we1[1] + e.z * we1[2] + e.w * we1[3];
        float2 kv0 = h2f2(kv.x), kv1 = h2f2(kv.y);
        float p = q.x * (kv0.x + e0) + q.y * (kv1.x + e1);
        #pragma unroll
        for (int off = 1; off < 16; off <<= 1) p += __shfl_xor(p, off, 64);
        float x = __expf(p * SC);
        z += x;
        acc0 += x * (kv0.y + e0);
        acc1 += x * (kv1.y + e1);
    }
    float inv = 1.f / (z + 1e-16f);
    size_t oi = (size_t)n * 64 + lane;
    float2 o = Out[oi];
    o.x += acc0 * inv;
    o.y += acc1 * inv;
    Out[oi] = o;
}

// ---- fused final transform + MLP head, register weights, rotated stage-T reads ------
__global__ __launch_bounds__(512) void head2_kernel(const float* __restrict__ Outb,
        const float* __restrict__ Wt, const float* __restrict__ bt,
        const float* __restrict__ W1, const float* __restrict__ b1,
        const float* __restrict__ W2, const float* __restrict__ b2,
        const float* __restrict__ W3, const float* __restrict__ b3,
        float* __restrict__ out) {
    __shared__ __align__(16) float os[QNPB * HC];   // 25.6 KB; reused as d1s
    __shared__ __align__(16) float hs[QNPB * EMB];  // 6.4 KB
    __shared__ __align__(16) float d2s[QNPB * 64];  // 12.8 KB
    float* d1s = os;                     // alias: os dead once hs is built
    int tid = threadIdx.x;
    int node0 = blockIdx.x * QNPB;
    int g = tid >> 7;                    // 4 node-groups (2 waves each)

    {   // float4 staging copy
        const float4* src4 = (const float4*)(Outb + (size_t)node0 * HC);
        float4* dst4 = (float4*)os;
        for (int i = tid; i < QNPB * HC / 4; i += 512) dst4[i] = src4[i];
    }

    // stage T (rotated reads)
    int cT = (tid & 127) >> 2, seg = tid & 3;
    float wt[32];
    #pragma unroll
    for (int j = 0; j < 32; ++j) wt[j] = Wt[(seg * 32 + j) * EMB + cT];
    float btc = bt[cT];
    __syncthreads();
    for (int k = g; k < QNPB; k += 4) {
        float p = 0.f;
        const float4* r4 = (const float4*)(os + k * HC + seg * 32);
        #pragma unroll
        for (int jj = 0; jj < 8; ++jj) {
            int j4 = (seg * 2 + jj) & 7;
            float4 rv = r4[j4];
            p += rv.x * wt[4 * j4] + rv.y * wt[4 * j4 + 1]
               + rv.z * wt[4 * j4 + 2] + rv.w * wt[4 * j4 + 3];
        }
        p += __shfl_xor(p, 1, 64);
        p += __shfl_xor(p, 2, 64);
        if (seg == 0) hs[k * EMB + cT] = fmaxf(p + btc, 0.f);
    }
    __syncthreads();

    // stage 1: d1 = relu(b1 + h @ W1)
    int c1 = tid & 127;
    float w1[32];
    #pragma unroll
    for (int f = 0; f < 32; ++f) w1[f] = W1[f * DENSE + c1];
    float b1c = b1[c1];
    const float4* hs4 = (const float4*)hs;
    for (int k = g; k < QNPB; k += 4) {
        float s = b1c;
        #pragma unroll
        for (int f4 = 0; f4 < 8; ++f4) {
            float4 hv = hs4[k * 8 + f4];
            s += hv.x * w1[4 * f4] + hv.y * w1[4 * f4 + 1]
               + hv.z * w1[4 * f4 + 2] + hv.w * w1[4 * f4 + 3];
        }
        d1s[k * DENSE + c1] = fmaxf(s, 0.f);
    }
    __syncthreads();

    // stage 2: d2 = relu(b2 + d1 @ W2)   (2-way LDS aliasing — free)
    int c2 = (tid & 127) >> 1, hh = tid & 1;
    float w2[64];
    #pragma unroll
    for (int j = 0; j < 64; ++j) w2[j] = W2[(hh * 64 + j) * 64 + c2];
    float b2c = b2[c2];
    for (int k = g; k < QNPB; k += 4) {
        float p = 0.f;
        const float4* r4 = (const float4*)(d1s + k * DENSE + hh * 64);
        #pragma unroll
        for (int j4 = 0; j4 < 16; ++j4) {
            float4 rv = r4[j4];
            p += rv.x * w2[4 * j4] + rv.y * w2[4 * j4 + 1]
               + rv.z * w2[4 * j4 + 2] + rv.w * w2[4 * j4 + 3];
        }
        p += __shfl_xor(p, 1, 64);
        if (hh == 0) d2s[k * 64 + c2] = fmaxf(p + b2c, 0.f);
    }
    __syncthreads();

    // stage 3
    int w = tid >> 6, lane = tid & 63;
    float w3r = W3[lane];
    float b3r = b3[0];
    for (int k = w; k < QNPB; k += 8) {
        float t = d2s[k * 64 + lane] * w3r;
        #pragma unroll
        for (int off = 1; off < 64; off <<= 1) t += __shfl_xor(t, off, 64);
        if (lane == 0) out[node0 + k] = 1.f / (1.f + __expf(-(t + b3r)));
    }
}

extern "C" void kernel_launch(void* const* d_in, const int* in_sizes, int n_in,
                              void* d_out, int out_size, void* d_ws, size_t ws_size,
                              hipStream_t stream) {
    const float* x   = (const float*)d_in[0];
    const int*   ei  = (const int*)d_in[1];    // [2,E]: src=ei, dst=ei+E
    const float* ea  = (const float*)d_in[2];
    const float* Wq0 = (const float*)d_in[3];  const float* bq0 = (const float*)d_in[4];
    const float* Wk0 = (const float*)d_in[5];  const float* bk0 = (const float*)d_in[6];
    const float* Wv0 = (const float*)d_in[7];  const float* bv0 = (const float*)d_in[8];
    const float* We0 = (const float*)d_in[9];
    const float* Ws0 = (const float*)d_in[10]; const float* bs0 = (const float*)d_in[11];
    const float* Wt0 = (const float*)d_in[12]; const float* bt0 = (const float*)d_in[13];
    const float* WqL = (const float*)d_in[14]; const float* bqL = (const float*)d_in[15];
    const float* WkL = (const float*)d_in[16]; const float* bkL = (const float*)d_in[17];
    const float* WvL = (const float*)d_in[18]; const float* bvL = (const float*)d_in[19];
    const float* WeL = (const float*)d_in[20];
    const float* WsL = (const float*)d_in[21]; const float* bsL = (const float*)d_in[22];
    const float* WtL = (const float*)d_in[23]; const float* btL = (const float*)d_in[24];
    const float* W1  = (const float*)d_in[25]; const float* b1  = (const float*)d_in[26];
    const float* W2  = (const float*)d_in[27]; const float* b2  = (const float*)d_in[28];
    const float* W3  = (const float*)d_in[29]; const float* b3  = (const float*)d_in[30];
    float* out = (float*)d_out;

    char* ws = (char*)d_ws;
    size_t off = 0;
    auto alloc = [&](size_t bytes) -> void* {
        void* p = ws + off; off = (off + bytes + 255) & ~(size_t)255; return p;
    };
    int*     cursor  = (int*)    alloc((size_t)NN * 4);
    int*     row_ptr = (int*)    alloc((size_t)(NN + 1) * 4);
    int*     bsum    = (int*)    alloc((size_t)SBLK * 4);
    int*     ssrc    = (int*)    alloc((size_t)EE * 4);
    float4*  sea     = (float4*) alloc((size_t)EE * 16);
    float*   Q       = (float*)  alloc((size_t)NN * HC * 4);
    uint*    kvu     = (uint*)   alloc((size_t)NN * HC * 2 * 2);   // (k,v) packed fp16
    float*   Outb    = (float*)  alloc((size_t)NN * HC * 4);
    // total ~93 MB

    // ---- CSR by dst (edge_index shared by all 3 conv layers) ----
    hipMemsetAsync(cursor, 0, (size_t)NN * 4, stream);
    hist_kernel<<<(EE + 255) / 256, 256, 0, stream>>>(ei + EE, cursor);
    scan1_kernel<<<SBLK, 1024, 0, stream>>>(cursor, row_ptr, bsum);
    scan2_kernel<<<1, 64, 0, stream>>>(bsum, row_ptr);
    scan3_kernel<<<SBLK, 1024, 0, stream>>>(row_ptr, cursor, bsum);
    scatter_kernel<<<(EE + 255) / 256, 256, 0, stream>>>(ei, ei + EE, ea, cursor, ssrc, sea);

    const uint2* kvp = (const uint2*)kvu;
    float2* Out2 = (float2*)Outb;

    // ---- layer 0 ----
    qkvs0_kernel<<<NN / QNPB, 512, 0, stream>>>(x, Wq0, bq0, Wk0, bk0, Wv0, bv0,
                                                Ws0, bs0, Q, kvu, Outb);
    edge_attn_kernel<<<NN / 4, 256, 0, stream>>>(row_ptr, ssrc, sea, We0, Q, kvp, Out2);

    // ---- layer 1 ----
    ftq_kernel<<<NN / QNPB, 512, 0, stream>>>(Wt0, bt0,
        WqL, bqL, WkL, bkL, WvL, bvL, WsL, bsL, Q, kvu, Outb);
    edge_attn_kernel<<<NN / 4, 256, 0, stream>>>(row_ptr, ssrc, sea, WeL, Q, kvp, Out2);

    // ---- layer 2 ----
    ftq_kernel<<<NN / QNPB, 512, 0, stream>>>(WtL, btL,
        WqL + EMB * HC, bqL + HC, WkL + EMB * HC, bkL + HC,
        WvL + EMB * HC, bvL + HC, WsL + EMB * HC, bsL + HC, Q, kvu, Outb);
    edge_attn_kernel<<<NN / 4, 256, 0, stream>>>(row_ptr, ssrc, sea,
        WeL + EDIM * HC, Q, kvp, Out2);

    // ---- fused final transform + register-weight MLP head ----
    head2_kernel<<<NN / QNPB, 512, 0, stream>>>(Outb, WtL + (size_t)HC * EMB, btL + EMB,
                                                W1, b1, W2, b2, W3, b3, out);
}

// Round 14
// 694.440 us; speedup vs baseline: 1.0367x; 1.0367x over previous
//
#include <hip/hip_runtime.h>

#define NN 50000
#define EE 800000
#define FIN 16
#define EDIM 4
#define EMB 32
#define NH 4
#define HC 128          // EMB*NH
#define NL 2
#define DENSE 128
#define QNPB 50         // nodes per qkvs/ftq/head block (50000 = 1000 * 50)
#define SBLK 49         // scan blocks: ceil(50000/1024)

// unpack two packed fp16 -> float2
__device__ __forceinline__ float2 h2f2(unsigned int u) {
    union { unsigned int u; _Float16 h[2]; } c; c.u = u;
    return make_float2((float)c.h[0], (float)c.h[1]);
}

// ---------------- CSR build ----------------
__global__ void hist_kernel(const int* __restrict__ dst, int* __restrict__ counts) {
    int e = blockIdx.x * blockDim.x + threadIdx.x;
    if (e < EE) atomicAdd(&counts[dst[e]], 1);
}

__global__ __launch_bounds__(1024) void scan1_kernel(const int* __restrict__ cursor,
                                                     int* __restrict__ row_ptr,
                                                     int* __restrict__ bsum) {
    __shared__ int wsum[16];
    __shared__ int wpre[17];
    int tid = threadIdx.x, lane = tid & 63, wid = tid >> 6;
    int i = blockIdx.x * 1024 + tid;
    int v = (i < NN) ? cursor[i] : 0;
    int incl = v;
    #pragma unroll
    for (int off = 1; off < 64; off <<= 1) {
        int t = __shfl_up(incl, off, 64);
        if (lane >= off) incl += t;
    }
    if (lane == 63) wsum[wid] = incl;
    __syncthreads();
    if (tid == 0) {
        int acc = 0;
        #pragma unroll
        for (int w = 0; w < 16; ++w) { wpre[w] = acc; acc += wsum[w]; }
        wpre[16] = acc;
    }
    __syncthreads();
    if (i < NN) row_ptr[i] = wpre[wid] + incl - v;
    if (tid == 0) bsum[blockIdx.x] = wpre[16];
}

__global__ void scan2_kernel(int* __restrict__ bsum, int* __restrict__ row_ptr) {
    int t = threadIdx.x;                               // 64 threads
    int v = (t < SBLK) ? bsum[t] : 0;
    int incl = v;
    #pragma unroll
    for (int off = 1; off < 64; off <<= 1) {
        int u = __shfl_up(incl, off, 64);
        if (t >= off) incl += u;
    }
    if (t < SBLK) bsum[t] = incl - v;
    if (t == 63) row_ptr[NN] = incl;
}

__global__ __launch_bounds__(1024) void scan3_kernel(int* __restrict__ row_ptr,
                                                     int* __restrict__ cursor,
                                                     const int* __restrict__ bsum) {
    int i = blockIdx.x * 1024 + threadIdx.x;
    if (i >= NN) return;
    int r = row_ptr[i] + bsum[blockIdx.x];
    row_ptr[i] = r;
    cursor[i] = r;
}

__global__ void scatter_kernel(const int* __restrict__ src, const int* __restrict__ dst,
                               const float* __restrict__ ea, int* __restrict__ cursor,
                               int* __restrict__ ssrc, float4* __restrict__ sea) {
    int e = blockIdx.x * blockDim.x + threadIdx.x;
    if (e >= EE) return;
    int d = dst[e];
    int pos = atomicAdd(&cursor[d], 1);
    ssrc[pos] = src[e];
    sea[pos] = *reinterpret_cast<const float4*>(ea + (size_t)e * 4);
}

// ------- layer-0 projections: Q f32, K/V packed fp16, skip into Out; f4 LDS ---------
__global__ __launch_bounds__(512) void qkvs0_kernel(const float* __restrict__ x,
        const float* __restrict__ Wq, const float* __restrict__ bq,
        const float* __restrict__ Wk, const float* __restrict__ bk,
        const float* __restrict__ Wv, const float* __restrict__ bv,
        const float* __restrict__ Ws, const float* __restrict__ bs,
        float* __restrict__ Q, _Float16* __restrict__ kvh,
        float* __restrict__ Out) {
    __shared__ __align__(16) float hs[QNPB * FIN];
    int tid = threadIdx.x;
    int m = tid >> 7, c = tid & 127;
    const float* W; const float* b;
    switch (m) {
        case 0:  W = Wq; b = bq; break;
        case 1:  W = Wk; b = bk; break;
        case 2:  W = Wv; b = bv; break;
        default: W = Ws; b = bs; break;
    }
    float w[FIN];
    #pragma unroll
    for (int f = 0; f < FIN; ++f) w[f] = W[f * HC + c];
    float bias = b[c];
    int node0 = blockIdx.x * QNPB;
    {   // float4 staging copy
        const float4* src4 = (const float4*)(x + (size_t)node0 * FIN);
        float4* dst4 = (float4*)hs;
        for (int i = tid; i < QNPB * FIN / 4; i += 512) dst4[i] = src4[i];
    }
    __syncthreads();
    const float4* hs4 = (const float4*)hs;
    for (int k = 0; k < QNPB; ++k) {
        float s = bias;
        #pragma unroll
        for (int f4 = 0; f4 < FIN / 4; ++f4) {
            float4 hv = hs4[k * (FIN / 4) + f4];
            s += hv.x * w[4 * f4] + hv.y * w[4 * f4 + 1]
               + hv.z * w[4 * f4 + 2] + hv.w * w[4 * f4 + 3];
        }
        size_t n = node0 + k;
        if      (m == 0) Q[n * HC + c] = s;
        else if (m == 1) kvh[n * 256 + 2 * c] = (_Float16)s;
        else if (m == 2) kvh[n * 256 + 2 * c + 1] = (_Float16)s;
        else             Out[n * HC + c] = s;
    }
}

// ---- fused transform + projections, register-cached Wt, rotated stage-T reads ------
__global__ __launch_bounds__(512) void ftq_kernel(const float* __restrict__ Wt,
        const float* __restrict__ bt,
        const float* __restrict__ Wq, const float* __restrict__ bq,
        const float* __restrict__ Wk, const float* __restrict__ bk,
        const float* __restrict__ Wv, const float* __restrict__ bv,
        const float* __restrict__ Ws, const float* __restrict__ bs,
        float* __restrict__ Q, _Float16* __restrict__ kvh,
        float* __restrict__ Out) {
    __shared__ __align__(16) float os[QNPB * HC];   // 25.6 KB
    __shared__ __align__(16) float hs[QNPB * EMB];  // 6.4 KB
    int tid = threadIdx.x;
    int node0 = blockIdx.x * QNPB;
    int g = tid >> 7;                   // 4 node-groups (2 waves each)

    {   // float4 staging copy
        const float4* src4 = (const float4*)(Out + (size_t)node0 * HC);
        float4* dst4 = (float4*)os;
        for (int i = tid; i < QNPB * HC / 4; i += 512) dst4[i] = src4[i];
    }

    // stage T: h = relu(bt + Out @ Wt). thread (g, cT=(tid&127)>>2, seg=tid&3)
    int cT = (tid & 127) >> 2, seg = tid & 3;
    float wt[32];
    #pragma unroll
    for (int j = 0; j < 32; ++j) wt[j] = Wt[(seg * 32 + j) * EMB + cT];
    float btc = bt[cT];
    __syncthreads();
    for (int k = g; k < QNPB; k += 4) {
        float p = 0.f;
        const float4* r4 = (const float4*)(os + k * HC + seg * 32);
        #pragma unroll
        for (int jj = 0; jj < 8; ++jj) {
            int j4 = (seg * 2 + jj) & 7;        // rotate: break 4-way bank conflict
            float4 rv = r4[j4];
            p += rv.x * wt[4 * j4] + rv.y * wt[4 * j4 + 1]
               + rv.z * wt[4 * j4 + 2] + rv.w * wt[4 * j4 + 3];
        }
        p += __shfl_xor(p, 1, 64);      // seg pairs
        p += __shfl_xor(p, 2, 64);
        if (seg == 0) hs[k * EMB + cT] = fmaxf(p + btc, 0.f);
    }
    __syncthreads();

    // stage QKVS: weights in registers (EMB=32/thread), float4 h reads
    int m = tid >> 7, c = tid & 127;
    const float* W; const float* b;
    switch (m) {
        case 0:  W = Wq; b = bq; break;
        case 1:  W = Wk; b = bk; break;
        case 2:  W = Wv; b = bv; break;
        default: W = Ws; b = bs; break;
    }
    float w[EMB];
    #pragma unroll
    for (int f = 0; f < EMB; ++f) w[f] = W[f * HC + c];
    float bias = b[c];
    const float4* hs4 = (const float4*)hs;
    for (int k = 0; k < QNPB; ++k) {
        float s = bias;
        #pragma unroll
        for (int f4 = 0; f4 < EMB / 4; ++f4) {
            float4 hv = hs4[k * (EMB / 4) + f4];
            s += hv.x * w[4 * f4] + hv.y * w[4 * f4 + 1]
               + hv.z * w[4 * f4 + 2] + hv.w * w[4 * f4 + 3];
        }
        size_t n = node0 + k;
        if      (m == 0) Q[n * HC + c] = s;
        else if (m == 1) kvh[n * 256 + 2 * c] = (_Float16)s;
        else if (m == 2) kvh[n * 256 + 2 * c + 1] = (_Float16)s;
        else             Out[n * HC + c] = s;
    }
}

// ------- edge attention (round-9/11 version: 24 VGPR, occupancy-optimal) -------------
__global__ __launch_bounds__(256) void edge_attn_kernel(const int* __restrict__ row_ptr,
        const int* __restrict__ ssrc, const float4* __restrict__ sea,
        const float* __restrict__ We,
        const float* __restrict__ Q, const uint2* __restrict__ kvp,
        float2* __restrict__ Out) {
    int n = blockIdx.x * 4 + (threadIdx.x >> 6);   // grid*4 == NN exactly
    int lane = threadIdx.x & 63;
    int ch0 = 2 * lane, ch1 = 2 * lane + 1;
    float we0[4], we1[4];
    #pragma unroll
    for (int d = 0; d < 4; ++d) { we0[d] = We[d * HC + ch0]; we1[d] = We[d * HC + ch1]; }
    float2 q = ((const float2*)Q)[(size_t)n * 64 + lane];
    int start = row_ptr[n], end = row_ptr[n + 1];
    float z = 0.f, acc0 = 0.f, acc1 = 0.f;
    const float SC = 0.17677669529663687f;  // 1/sqrt(32)
    int i = start;
    for (; i + 1 < end; i += 2) {
        int sA = ssrc[i], sB = ssrc[i + 1];
        sA = sA < 0 ? 0 : (sA >= NN ? NN - 1 : sA);
        sB = sB < 0 ? 0 : (sB >= NN ? NN - 1 : sB);
        float4 eA = sea[i], eB = sea[i + 1];                     // wave-uniform
        uint2 kvA = kvp[(size_t)sA * 64 + lane];                 // k0,v0,k1,v1 fp16
        uint2 kvB = kvp[(size_t)sB * 64 + lane];
        float eA0 = eA.x * we0[0] + eA.y * we0[1] + eA.z * we0[2] + eA.w * we0[3];
        float eA1 = eA.x * we1[0] + eA.y * we1[1] + eA.z * we1[2] + eA.w * we1[3];
        float eB0 = eB.x * we0[0] + eB.y * we0[1] + eB.z * we0[2] + eB.w * we0[3];
        float eB1 = eB.x * we1[0] + eB.y * we1[1] + eB.z * we1[2] + eB.w * we1[3];
        float2 kvA0 = h2f2(kvA.x), kvA1 = h2f2(kvA.y);           // (k,v) ch0 / ch1
        float2 kvB0 = h2f2(kvB.x), kvB1 = h2f2(kvB.y);
        float pA = q.x * (kvA0.x + eA0) + q.y * (kvA1.x + eA1);
        float pB = q.x * (kvB0.x + eB0) + q.y * (kvB1.x + eB1);
        #pragma unroll
        for (int off = 1; off < 16; off <<= 1) {                 // 16-lane head groups
            pA += __shfl_xor(pA, off, 64);
            pB += __shfl_xor(pB, off, 64);
        }
        float xA = __expf(pA * SC), xB = __expf(pB * SC);
        z += xA + xB;
        acc0 += xA * (kvA0.y + eA0) + xB * (kvB0.y + eB0);
        acc1 += xA * (kvA1.y + eA1) + xB * (kvB1.y + eB1);
    }
    if (i < end) {
        int s = ssrc[i];
        s = s < 0 ? 0 : (s >= NN ? NN - 1 : s);
        float4 e = sea[i];
        uint2 kv = kvp[(size_t)s * 64 + lane];
        float e0 = e.x * we0[0] + e.y * we0[1] + e.z * we0[2] + e.w * we0[3];
        float e1 = e.x * we1[0] + e.y * we1[1] + e.z * we1[2] + e.w * we1[3];
        float2 kv0 = h2f2(kv.x), kv1 = h2f2(kv.y);
        float p = q.x * (kv0.x + e0) + q.y * (kv1.x + e1);
        #pragma unroll
        for (int off = 1; off < 16; off <<= 1) p += __shfl_xor(p, off, 64);
        float x = __expf(p * SC);
        z += x;
        acc0 += x * (kv0.y + e0);
        acc1 += x * (kv1.y + e1);
    }
    float inv = 1.f / (z + 1e-16f);
    size_t oi = (size_t)n * 64 + lane;
    float2 o = Out[oi];
    o.x += acc0 * inv;
    o.y += acc1 * inv;
    Out[oi] = o;
}

// ---- fused final transform + MLP head, register weights, rotated stage-T reads ------
__global__ __launch_bounds__(512) void head2_kernel(const float* __restrict__ Outb,
        const float* __restrict__ Wt, const float* __restrict__ bt,
        const float* __restrict__ W1, const float* __restrict__ b1,
        const float* __restrict__ W2, const float* __restrict__ b2,
        const float* __restrict__ W3, const float* __restrict__ b3,
        float* __restrict__ out) {
    __shared__ __align__(16) float os[QNPB * HC];   // 25.6 KB; reused as d1s
    __shared__ __align__(16) float hs[QNPB * EMB];  // 6.4 KB
    __shared__ __align__(16) float d2s[QNPB * 64];  // 12.8 KB
    float* d1s = os;                     // alias: os dead once hs is built
    int tid = threadIdx.x;
    int node0 = blockIdx.x * QNPB;
    int g = tid >> 7;                    // 4 node-groups (2 waves each)

    {   // float4 staging copy
        const float4* src4 = (const float4*)(Outb + (size_t)node0 * HC);
        float4* dst4 = (float4*)os;
        for (int i = tid; i < QNPB * HC / 4; i += 512) dst4[i] = src4[i];
    }

    // stage T (rotated reads)
    int cT = (tid & 127) >> 2, seg = tid & 3;
    float wt[32];
    #pragma unroll
    for (int j = 0; j < 32; ++j) wt[j] = Wt[(seg * 32 + j) * EMB + cT];
    float btc = bt[cT];
    __syncthreads();
    for (int k = g; k < QNPB; k += 4) {
        float p = 0.f;
        const float4* r4 = (const float4*)(os + k * HC + seg * 32);
        #pragma unroll
        for (int jj = 0; jj < 8; ++jj) {
            int j4 = (seg * 2 + jj) & 7;        // rotate: break 4-way bank conflict
            float4 rv = r4[j4];
            p += rv.x * wt[4 * j4] + rv.y * wt[4 * j4 + 1]
               + rv.z * wt[4 * j4 + 2] + rv.w * wt[4 * j4 + 3];
        }
        p += __shfl_xor(p, 1, 64);
        p += __shfl_xor(p, 2, 64);
        if (seg == 0) hs[k * EMB + cT] = fmaxf(p + btc, 0.f);
    }
    __syncthreads();

    // stage 1: d1 = relu(b1 + h @ W1)
    int c1 = tid & 127;
    float w1[32];
    #pragma unroll
    for (int f = 0; f < 32; ++f) w1[f] = W1[f * DENSE + c1];
    float b1c = b1[c1];
    const float4* hs4 = (const float4*)hs;
    for (int k = g; k < QNPB; k += 4) {
        float s = b1c;
        #pragma unroll
        for (int f4 = 0; f4 < 8; ++f4) {
            float4 hv = hs4[k * 8 + f4];
            s += hv.x * w1[4 * f4] + hv.y * w1[4 * f4 + 1]
               + hv.z * w1[4 * f4 + 2] + hv.w * w1[4 * f4 + 3];
        }
        d1s[k * DENSE + c1] = fmaxf(s, 0.f);
    }
    __syncthreads();

    // stage 2: d2 = relu(b2 + d1 @ W2)   (2-way LDS aliasing — free per m136)
    int c2 = (tid & 127) >> 1, hh = tid & 1;
    float w2[64];
    #pragma unroll
    for (int j = 0; j < 64; ++j) w2[j] = W2[(hh * 64 + j) * 64 + c2];
    float b2c = b2[c2];
    for (int k = g; k < QNPB; k += 4) {
        float p = 0.f;
        const float4* r4 = (const float4*)(d1s + k * DENSE + hh * 64);
        #pragma unroll
        for (int j4 = 0; j4 < 16; ++j4) {
            float4 rv = r4[j4];
            p += rv.x * w2[4 * j4] + rv.y * w2[4 * j4 + 1]
               + rv.z * w2[4 * j4 + 2] + rv.w * w2[4 * j4 + 3];
        }
        p += __shfl_xor(p, 1, 64);
        if (hh == 0) d2s[k * 64 + c2] = fmaxf(p + b2c, 0.f);
    }
    __syncthreads();

    // stage 3
    int w = tid >> 6, lane = tid & 63;
    float w3r = W3[lane];
    float b3r = b3[0];
    for (int k = w; k < QNPB; k += 8) {
        float t = d2s[k * 64 + lane] * w3r;
        #pragma unroll
        for (int off = 1; off < 64; off <<= 1) t += __shfl_xor(t, off, 64);
        if (lane == 0) out[node0 + k] = 1.f / (1.f + __expf(-(t + b3r)));
    }
}

extern "C" void kernel_launch(void* const* d_in, const int* in_sizes, int n_in,
                              void* d_out, int out_size, void* d_ws, size_t ws_size,
                              hipStream_t stream) {
    const float* x   = (const float*)d_in[0];
    const int*   ei  = (const int*)d_in[1];    // [2,E]: src=ei, dst=ei+E
    const float* ea  = (const float*)d_in[2];
    const float* Wq0 = (const float*)d_in[3];  const float* bq0 = (const float*)d_in[4];
    const float* Wk0 = (const float*)d_in[5];  const float* bk0 = (const float*)d_in[6];
    const float* Wv0 = (const float*)d_in[7];  const float* bv0 = (const float*)d_in[8];
    const float* We0 = (const float*)d_in[9];
    const float* Ws0 = (const float*)d_in[10]; const float* bs0 = (const float*)d_in[11];
    const float* Wt0 = (const float*)d_in[12]; const float* bt0 = (const float*)d_in[13];
    const float* WqL = (const float*)d_in[14]; const float* bqL = (const float*)d_in[15];
    const float* WkL = (const float*)d_in[16]; const float* bkL = (const float*)d_in[17];
    const float* WvL = (const float*)d_in[18]; const float* bvL = (const float*)d_in[19];
    const float* WeL = (const float*)d_in[20];
    const float* WsL = (const float*)d_in[21]; const float* bsL = (const float*)d_in[22];
    const float* WtL = (const float*)d_in[23]; const float* btL = (const float*)d_in[24];
    const float* W1  = (const float*)d_in[25]; const float* b1  = (const float*)d_in[26];
    const float* W2  = (const float*)d_in[27]; const float* b2  = (const float*)d_in[28];
    const float* W3  = (const float*)d_in[29]; const float* b3  = (const float*)d_in[30];
    float* out = (float*)d_out;

    char* ws = (char*)d_ws;
    size_t off = 0;
    auto alloc = [&](size_t bytes) -> void* {
        void* p = ws + off; off = (off + bytes + 255) & ~(size_t)255; return p;
    };
    int*     cursor  = (int*)    alloc((size_t)NN * 4);
    int*     row_ptr = (int*)    alloc((size_t)(NN + 1) * 4);
    int*     bsum    = (int*)    alloc((size_t)SBLK * 4);
    int*     ssrc    = (int*)    alloc((size_t)EE * 4);
    float4*  sea     = (float4*) alloc((size_t)EE * 16);
    float*   Q       = (float*)  alloc((size_t)NN * HC * 4);
    _Float16* kvh    = (_Float16*)alloc((size_t)NN * HC * 2 * 2);  // (k,v) interleaved
    float*   Outb    = (float*)  alloc((size_t)NN * HC * 4);
    // total ~93 MB

    // ---- CSR by dst (edge_index shared by all 3 conv layers) ----
    hipMemsetAsync(cursor, 0, (size_t)NN * 4, stream);
    hist_kernel<<<(EE + 255) / 256, 256, 0, stream>>>(ei + EE, cursor);
    scan1_kernel<<<SBLK, 1024, 0, stream>>>(cursor, row_ptr, bsum);
    scan2_kernel<<<1, 64, 0, stream>>>(bsum, row_ptr);
    scan3_kernel<<<SBLK, 1024, 0, stream>>>(row_ptr, cursor, bsum);
    scatter_kernel<<<(EE + 255) / 256, 256, 0, stream>>>(ei, ei + EE, ea, cursor, ssrc, sea);

    const uint2* kvp = (const uint2*)kvh;
    float2* Out2 = (float2*)Outb;

    // ---- layer 0 ----
    qkvs0_kernel<<<NN / QNPB, 512, 0, stream>>>(x, Wq0, bq0, Wk0, bk0, Wv0, bv0,
                                                Ws0, bs0, Q, kvh, Outb);
    edge_attn_kernel<<<NN / 4, 256, 0, stream>>>(row_ptr, ssrc, sea, We0, Q, kvp, Out2);

    // ---- layer 1 ----
    ftq_kernel<<<NN / QNPB, 512, 0, stream>>>(Wt0, bt0,
        WqL, bqL, WkL, bkL, WvL, bvL, WsL, bsL, Q, kvh, Outb);
    edge_attn_kernel<<<NN / 4, 256, 0, stream>>>(row_ptr, ssrc, sea, WeL, Q, kvp, Out2);

    // ---- layer 2 ----
    ftq_kernel<<<NN / QNPB, 512, 0, stream>>>(WtL, btL,
        WqL + EMB * HC, bqL + HC, WkL + EMB * HC, bkL + HC,
        WvL + EMB * HC, bvL + HC, WsL + EMB * HC, bsL + HC, Q, kvh, Outb);
    edge_attn_kernel<<<NN / 4, 256, 0, stream>>>(row_ptr, ssrc, sea,
        WeL + EDIM * HC, Q, kvp, Out2);

    // ---- fused final transform + register-weight MLP head ----
    head2_kernel<<<NN / QNPB, 512, 0, stream>>>(Outb, WtL + (size_t)HC * EMB, btL + EMB,
                                                W1, b1, W2, b2, W3, b3, out);
}

// Round 15
// 630.199 us; speedup vs baseline: 1.1424x; 1.1019x over previous
//
#include <hip/hip_runtime.h>

#define NN 50000
#define EE 800000
#define FIN 16
#define EDIM 4
#define EMB 32
#define NH 4
#define HC 128          // EMB*NH
#define NL 2
#define DENSE 128
#define QNPB 50         // nodes per qkvs/ftq/head block (50000 = 1000 * 50)
#define SBLK 49         // scan blocks: ceil(50000/1024)

// unpack two packed fp16 -> float2
__device__ __forceinline__ float2 h2f2(unsigned int u) {
    union { unsigned int u; _Float16 h[2]; } c; c.u = u;
    return make_float2((float)c.h[0], (float)c.h[1]);
}
__device__ __forceinline__ unsigned int pkh2(float a, float b) {
    union { unsigned int u; _Float16 h[2]; } c;
    c.h[0] = (_Float16)a; c.h[1] = (_Float16)b; return c.u;
}

// ---------------- CSR build ----------------
__global__ void hist_kernel(const int* __restrict__ dst, int* __restrict__ counts) {
    int e = blockIdx.x * blockDim.x + threadIdx.x;
    if (e < EE) atomicAdd(&counts[dst[e]], 1);
}

__global__ __launch_bounds__(1024) void scan1_kernel(const int* __restrict__ cursor,
                                                     int* __restrict__ row_ptr,
                                                     int* __restrict__ bsum) {
    __shared__ int wsum[16];
    __shared__ int wpre[17];
    int tid = threadIdx.x, lane = tid & 63, wid = tid >> 6;
    int i = blockIdx.x * 1024 + tid;
    int v = (i < NN) ? cursor[i] : 0;
    int incl = v;
    #pragma unroll
    for (int off = 1; off < 64; off <<= 1) {
        int t = __shfl_up(incl, off, 64);
        if (lane >= off) incl += t;
    }
    if (lane == 63) wsum[wid] = incl;
    __syncthreads();
    if (tid == 0) {
        int acc = 0;
        #pragma unroll
        for (int w = 0; w < 16; ++w) { wpre[w] = acc; acc += wsum[w]; }
        wpre[16] = acc;
    }
    __syncthreads();
    if (i < NN) row_ptr[i] = wpre[wid] + incl - v;
    if (tid == 0) bsum[blockIdx.x] = wpre[16];
}

__global__ void scan2_kernel(int* __restrict__ bsum, int* __restrict__ row_ptr) {
    int t = threadIdx.x;                               // 64 threads
    int v = (t < SBLK) ? bsum[t] : 0;
    int incl = v;
    #pragma unroll
    for (int off = 1; off < 64; off <<= 1) {
        int u = __shfl_up(incl, off, 64);
        if (t >= off) incl += u;
    }
    if (t < SBLK) bsum[t] = incl - v;
    if (t == 63) row_ptr[NN] = incl;
}

__global__ __launch_bounds__(1024) void scan3_kernel(int* __restrict__ row_ptr,
                                                     int* __restrict__ cursor,
                                                     const int* __restrict__ bsum) {
    int i = blockIdx.x * 1024 + threadIdx.x;
    if (i >= NN) return;
    int r = row_ptr[i] + bsum[blockIdx.x];
    row_ptr[i] = r;
    cursor[i] = r;
}

__global__ void scatter_kernel(const int* __restrict__ src, const int* __restrict__ dst,
                               const float* __restrict__ ea, int* __restrict__ cursor,
                               int* __restrict__ ssrc, unsigned long long* __restrict__ sea) {
    int e = blockIdx.x * blockDim.x + threadIdx.x;
    if (e >= EE) return;
    int d = dst[e];
    int pos = atomicAdd(&cursor[d], 1);
    ssrc[pos] = src[e];
    float4 q = *reinterpret_cast<const float4*>(ea + (size_t)e * 4);
    unsigned long long lo = pkh2(q.x, q.y);
    unsigned long long hi = pkh2(q.z, q.w);
    sea[pos] = lo | (hi << 32);
}

// ------- layer-0 projections: Q fp16, K/V packed fp16, skip into Out; f4 LDS --------
__global__ __launch_bounds__(512) void qkvs0_kernel(const float* __restrict__ x,
        const float* __restrict__ Wq, const float* __restrict__ bq,
        const float* __restrict__ Wk, const float* __restrict__ bk,
        const float* __restrict__ Wv, const float* __restrict__ bv,
        const float* __restrict__ Ws, const float* __restrict__ bs,
        _Float16* __restrict__ Qh, _Float16* __restrict__ kvh,
        float* __restrict__ Out) {
    __shared__ __align__(16) float hs[QNPB * FIN];
    int tid = threadIdx.x;
    int m = tid >> 7, c = tid & 127;
    const float* W; const float* b;
    switch (m) {
        case 0:  W = Wq; b = bq; break;
        case 1:  W = Wk; b = bk; break;
        case 2:  W = Wv; b = bv; break;
        default: W = Ws; b = bs; break;
    }
    float w[FIN];
    #pragma unroll
    for (int f = 0; f < FIN; ++f) w[f] = W[f * HC + c];
    float bias = b[c];
    int node0 = blockIdx.x * QNPB;
    {   // float4 staging copy
        const float4* src4 = (const float4*)(x + (size_t)node0 * FIN);
        float4* dst4 = (float4*)hs;
        for (int i = tid; i < QNPB * FIN / 4; i += 512) dst4[i] = src4[i];
    }
    __syncthreads();
    const float4* hs4 = (const float4*)hs;
    for (int k = 0; k < QNPB; ++k) {
        float s = bias;
        #pragma unroll
        for (int f4 = 0; f4 < FIN / 4; ++f4) {
            float4 hv = hs4[k * (FIN / 4) + f4];
            s += hv.x * w[4 * f4] + hv.y * w[4 * f4 + 1]
               + hv.z * w[4 * f4 + 2] + hv.w * w[4 * f4 + 3];
        }
        size_t n = node0 + k;
        if      (m == 0) Qh[n * HC + c] = (_Float16)s;
        else if (m == 1) kvh[n * 256 + 2 * c] = (_Float16)s;
        else if (m == 2) kvh[n * 256 + 2 * c + 1] = (_Float16)s;
        else             Out[n * HC + c] = s;
    }
}

// ---- fused transform + projections, register-cached Wt (round-11 stage T) ----------
__global__ __launch_bounds__(512) void ftq_kernel(const float* __restrict__ Wt,
        const float* __restrict__ bt,
        const float* __restrict__ Wq, const float* __restrict__ bq,
        const float* __restrict__ Wk, const float* __restrict__ bk,
        const float* __restrict__ Wv, const float* __restrict__ bv,
        const float* __restrict__ Ws, const float* __restrict__ bs,
        _Float16* __restrict__ Qh, _Float16* __restrict__ kvh,
        float* __restrict__ Out) {
    __shared__ __align__(16) float os[QNPB * HC];   // 25.6 KB
    __shared__ __align__(16) float hs[QNPB * EMB];  // 6.4 KB
    int tid = threadIdx.x;
    int node0 = blockIdx.x * QNPB;
    int g = tid >> 7;                   // 4 node-groups (2 waves each)

    {   // float4 staging copy
        const float4* src4 = (const float4*)(Out + (size_t)node0 * HC);
        float4* dst4 = (float4*)os;
        for (int i = tid; i < QNPB * HC / 4; i += 512) dst4[i] = src4[i];
    }

    // stage T: h = relu(bt + Out @ Wt). thread (g, cT=(tid&127)>>2, seg=tid&3)
    int cT = (tid & 127) >> 2, seg = tid & 3;
    float wt[32];
    #pragma unroll
    for (int j = 0; j < 32; ++j) wt[j] = Wt[(seg * 32 + j) * EMB + cT];
    float btc = bt[cT];
    __syncthreads();
    for (int k = g; k < QNPB; k += 4) {
        float p = 0.f;
        const float4* r4 = (const float4*)(os + k * HC + seg * 32);
        #pragma unroll
        for (int j4 = 0; j4 < 8; ++j4) {
            float4 rv = r4[j4];
            p += rv.x * wt[4 * j4] + rv.y * wt[4 * j4 + 1]
               + rv.z * wt[4 * j4 + 2] + rv.w * wt[4 * j4 + 3];
        }
        p += __shfl_xor(p, 1, 64);      // seg pairs
        p += __shfl_xor(p, 2, 64);
        if (seg == 0) hs[k * EMB + cT] = fmaxf(p + btc, 0.f);
    }
    __syncthreads();

    // stage QKVS: weights in registers (EMB=32/thread), float4 h reads
    int m = tid >> 7, c = tid & 127;
    const float* W; const float* b;
    switch (m) {
        case 0:  W = Wq; b = bq; break;
        case 1:  W = Wk; b = bk; break;
        case 2:  W = Wv; b = bv; break;
        default: W = Ws; b = bs; break;
    }
    float w[EMB];
    #pragma unroll
    for (int f = 0; f < EMB; ++f) w[f] = W[f * HC + c];
    float bias = b[c];
    const float4* hs4 = (const float4*)hs;
    for (int k = 0; k < QNPB; ++k) {
        float s = bias;
        #pragma unroll
        for (int f4 = 0; f4 < EMB / 4; ++f4) {
            float4 hv = hs4[k * (EMB / 4) + f4];
            s += hv.x * w[4 * f4] + hv.y * w[4 * f4 + 1]
               + hv.z * w[4 * f4 + 2] + hv.w * w[4 * f4 + 3];
        }
        size_t n = node0 + k;
        if      (m == 0) Qh[n * HC + c] = (_Float16)s;
        else if (m == 1) kvh[n * 256 + 2 * c] = (_Float16)s;
        else if (m == 2) kvh[n * 256 + 2 * c + 1] = (_Float16)s;
        else             Out[n * HC + c] = s;
    }
}

// ------- edge attention: fp16 Q + fp16 sea + fp16 KV gather, 24-VGPR structure -------
__global__ __launch_bounds__(256) void edge_attn_kernel(const int* __restrict__ row_ptr,
        const int* __restrict__ ssrc, const unsigned long long* __restrict__ sea,
        const float* __restrict__ We,
        const _Float16* __restrict__ Qh, const uint2* __restrict__ kvp,
        float2* __restrict__ Out) {
    int n = blockIdx.x * 4 + (threadIdx.x >> 6);   // grid*4 == NN exactly
    int lane = threadIdx.x & 63;
    int ch0 = 2 * lane, ch1 = 2 * lane + 1;
    float we0[4], we1[4];
    #pragma unroll
    for (int d = 0; d < 4; ++d) { we0[d] = We[d * HC + ch0]; we1[d] = We[d * HC + ch1]; }
    float2 q = h2f2(((const unsigned int*)Qh)[(size_t)n * 64 + lane]);
    int start = row_ptr[n], end = row_ptr[n + 1];
    float z = 0.f, acc0 = 0.f, acc1 = 0.f;
    const float SC = 0.17677669529663687f;  // 1/sqrt(32)
    int i = start;
    for (; i + 1 < end; i += 2) {
        int sA = ssrc[i], sB = ssrc[i + 1];
        sA = sA < 0 ? 0 : (sA >= NN ? NN - 1 : sA);
        sB = sB < 0 ? 0 : (sB >= NN ? NN - 1 : sB);
        unsigned long long epA = sea[i], epB = sea[i + 1];       // wave-uniform
        uint2 kvA = kvp[(size_t)sA * 64 + lane];                 // k0,v0,k1,v1 fp16
        uint2 kvB = kvp[(size_t)sB * 64 + lane];
        float2 eAxy = h2f2((unsigned int)epA), eAzw = h2f2((unsigned int)(epA >> 32));
        float2 eBxy = h2f2((unsigned int)epB), eBzw = h2f2((unsigned int)(epB >> 32));
        float eA0 = eAxy.x * we0[0] + eAxy.y * we0[1] + eAzw.x * we0[2] + eAzw.y * we0[3];
        float eA1 = eAxy.x * we1[0] + eAxy.y * we1[1] + eAzw.x * we1[2] + eAzw.y * we1[3];
        float eB0 = eBxy.x * we0[0] + eBxy.y * we0[1] + eBzw.x * we0[2] + eBzw.y * we0[3];
        float eB1 = eBxy.x * we1[0] + eBxy.y * we1[1] + eBzw.x * we1[2] + eBzw.y * we1[3];
        float2 kvA0 = h2f2(kvA.x), kvA1 = h2f2(kvA.y);           // (k,v) ch0 / ch1
        float2 kvB0 = h2f2(kvB.x), kvB1 = h2f2(kvB.y);
        float pA = q.x * (kvA0.x + eA0) + q.y * (kvA1.x + eA1);
        float pB = q.x * (kvB0.x + eB0) + q.y * (kvB1.x + eB1);
        #pragma unroll
        for (int off = 1; off < 16; off <<= 1) {                 // 16-lane head groups
            pA += __shfl_xor(pA, off, 64);
            pB += __shfl_xor(pB, off, 64);
        }
        float xA = __expf(pA * SC), xB = __expf(pB * SC);
        z += xA + xB;
        acc0 += xA * (kvA0.y + eA0) + xB * (kvB0.y + eB0);
        acc1 += xA * (kvA1.y + eA1) + xB * (kvB1.y + eB1);
    }
    if (i < end) {
        int s = ssrc[i];
        s = s < 0 ? 0 : (s >= NN ? NN - 1 : s);
        unsigned long long ep = sea[i];
        uint2 kv = kvp[(size_t)s * 64 + lane];
        float2 exy = h2f2((unsigned int)ep), ezw = h2f2((unsigned int)(ep >> 32));
        float e0 = exy.x * we0[0] + exy.y * we0[1] + ezw.x * we0[2] + ezw.y * we0[3];
        float e1 = exy.x * we1[0] + exy.y * we1[1] + ezw.x * we1[2] + ezw.y * we1[3];
        float2 kv0 = h2f2(kv.x), kv1 = h2f2(kv.y);
        float p = q.x * (kv0.x + e0) + q.y * (kv1.x + e1);
        #pragma unroll
        for (int off = 1; off < 16; off <<= 1) p += __shfl_xor(p, off, 64);
        float x = __expf(p * SC);
        z += x;
        acc0 += x * (kv0.y + e0);
        acc1 += x * (kv1.y + e1);
    }
    float inv = 1.f / (z + 1e-16f);
    size_t oi = (size_t)n * 64 + lane;
    float2 o = Out[oi];
    o.x += acc0 * inv;
    o.y += acc1 * inv;
    Out[oi] = o;
}

// ---- fused final transform + MLP head, register weights (round-11 stage T) ----------
__global__ __launch_bounds__(512) void head2_kernel(const float* __restrict__ Outb,
        const float* __restrict__ Wt, const float* __restrict__ bt,
        const float* __restrict__ W1, const float* __restrict__ b1,
        const float* __restrict__ W2, const float* __restrict__ b2,
        const float* __restrict__ W3, const float* __restrict__ b3,
        float* __restrict__ out) {
    __shared__ __align__(16) float os[QNPB * HC];   // 25.6 KB; reused as d1s
    __shared__ __align__(16) float hs[QNPB * EMB];  // 6.4 KB
    __shared__ __align__(16) float d2s[QNPB * 64];  // 12.8 KB
    float* d1s = os;                     // alias: os dead once hs is built
    int tid = threadIdx.x;
    int node0 = blockIdx.x * QNPB;
    int g = tid >> 7;                    // 4 node-groups (2 waves each)

    {   // float4 staging copy
        const float4* src4 = (const float4*)(Outb + (size_t)node0 * HC);
        float4* dst4 = (float4*)os;
        for (int i = tid; i < QNPB * HC / 4; i += 512) dst4[i] = src4[i];
    }

    // stage T
    int cT = (tid & 127) >> 2, seg = tid & 3;
    float wt[32];
    #pragma unroll
    for (int j = 0; j < 32; ++j) wt[j] = Wt[(seg * 32 + j) * EMB + cT];
    float btc = bt[cT];
    __syncthreads();
    for (int k = g; k < QNPB; k += 4) {
        float p = 0.f;
        const float4* r4 = (const float4*)(os + k * HC + seg * 32);
        #pragma unroll
        for (int j4 = 0; j4 < 8; ++j4) {
            float4 rv = r4[j4];
            p += rv.x * wt[4 * j4] + rv.y * wt[4 * j4 + 1]
               + rv.z * wt[4 * j4 + 2] + rv.w * wt[4 * j4 + 3];
        }
        p += __shfl_xor(p, 1, 64);
        p += __shfl_xor(p, 2, 64);
        if (seg == 0) hs[k * EMB + cT] = fmaxf(p + btc, 0.f);
    }
    __syncthreads();

    // stage 1: d1 = relu(b1 + h @ W1)
    int c1 = tid & 127;
    float w1[32];
    #pragma unroll
    for (int f = 0; f < 32; ++f) w1[f] = W1[f * DENSE + c1];
    float b1c = b1[c1];
    const float4* hs4 = (const float4*)hs;
    for (int k = g; k < QNPB; k += 4) {
        float s = b1c;
        #pragma unroll
        for (int f4 = 0; f4 < 8; ++f4) {
            float4 hv = hs4[k * 8 + f4];
            s += hv.x * w1[4 * f4] + hv.y * w1[4 * f4 + 1]
               + hv.z * w1[4 * f4 + 2] + hv.w * w1[4 * f4 + 3];
        }
        d1s[k * DENSE + c1] = fmaxf(s, 0.f);
    }
    __syncthreads();

    // stage 2: d2 = relu(b2 + d1 @ W2)
    int c2 = (tid & 127) >> 1, hh = tid & 1;
    float w2[64];
    #pragma unroll
    for (int j = 0; j < 64; ++j) w2[j] = W2[(hh * 64 + j) * 64 + c2];
    float b2c = b2[c2];
    for (int k = g; k < QNPB; k += 4) {
        float p = 0.f;
        const float4* r4 = (const float4*)(d1s + k * DENSE + hh * 64);
        #pragma unroll
        for (int j4 = 0; j4 < 16; ++j4) {
            float4 rv = r4[j4];
            p += rv.x * w2[4 * j4] + rv.y * w2[4 * j4 + 1]
               + rv.z * w2[4 * j4 + 2] + rv.w * w2[4 * j4 + 3];
        }
        p += __shfl_xor(p, 1, 64);
        if (hh == 0) d2s[k * 64 + c2] = fmaxf(p + b2c, 0.f);
    }
    __syncthreads();

    // stage 3
    int w = tid >> 6, lane = tid & 63;
    float w3r = W3[lane];
    float b3r = b3[0];
    for (int k = w; k < QNPB; k += 8) {
        float t = d2s[k * 64 + lane] * w3r;
        #pragma unroll
        for (int off = 1; off < 64; off <<= 1) t += __shfl_xor(t, off, 64);
        if (lane == 0) out[node0 + k] = 1.f / (1.f + __expf(-(t + b3r)));
    }
}

extern "C" void kernel_launch(void* const* d_in, const int* in_sizes, int n_in,
                              void* d_out, int out_size, void* d_ws, size_t ws_size,
                              hipStream_t stream) {
    const float* x   = (const float*)d_in[0];
    const int*   ei  = (const int*)d_in[1];    // [2,E]: src=ei, dst=ei+E
    const float* ea  = (const float*)d_in[2];
    const float* Wq0 = (const float*)d_in[3];  const float* bq0 = (const float*)d_in[4];
    const float* Wk0 = (const float*)d_in[5];  const float* bk0 = (const float*)d_in[6];
    const float* Wv0 = (const float*)d_in[7];  const float* bv0 = (const float*)d_in[8];
    const float* We0 = (const float*)d_in[9];
    const float* Ws0 = (const float*)d_in[10]; const float* bs0 = (const float*)d_in[11];
    const float* Wt0 = (const float*)d_in[12]; const float* bt0 = (const float*)d_in[13];
    const float* WqL = (const float*)d_in[14]; const float* bqL = (const float*)d_in[15];
    const float* WkL = (const float*)d_in[16]; const float* bkL = (const float*)d_in[17];
    const float* WvL = (const float*)d_in[18]; const float* bvL = (const float*)d_in[19];
    const float* WeL = (const float*)d_in[20];
    const float* WsL = (const float*)d_in[21]; const float* bsL = (const float*)d_in[22];
    const float* WtL = (const float*)d_in[23]; const float* btL = (const float*)d_in[24];
    const float* W1  = (const float*)d_in[25]; const float* b1  = (const float*)d_in[26];
    const float* W2  = (const float*)d_in[27]; const float* b2  = (const float*)d_in[28];
    const float* W3  = (const float*)d_in[29]; const float* b3  = (const float*)d_in[30];
    float* out = (float*)d_out;

    char* ws = (char*)d_ws;
    size_t off = 0;
    auto alloc = [&](size_t bytes) -> void* {
        void* p = ws + off; off = (off + bytes + 255) & ~(size_t)255; return p;
    };
    int*      cursor  = (int*)     alloc((size_t)NN * 4);
    int*      row_ptr = (int*)     alloc((size_t)(NN + 1) * 4);
    int*      bsum    = (int*)     alloc((size_t)SBLK * 4);
    int*      ssrc    = (int*)     alloc((size_t)EE * 4);
    unsigned long long* sea = (unsigned long long*)alloc((size_t)EE * 8);
    _Float16* Qh      = (_Float16*)alloc((size_t)NN * HC * 2);
    _Float16* kvh     = (_Float16*)alloc((size_t)NN * HC * 2 * 2);  // (k,v) interleaved
    float*    Outb    = (float*)   alloc((size_t)NN * HC * 4);
    // total ~73 MB

    // ---- CSR by dst (edge_index shared by all 3 conv layers) ----
    hipMemsetAsync(cursor, 0, (size_t)NN * 4, stream);
    hist_kernel<<<(EE + 255) / 256, 256, 0, stream>>>(ei + EE, cursor);
    scan1_kernel<<<SBLK, 1024, 0, stream>>>(cursor, row_ptr, bsum);
    scan2_kernel<<<1, 64, 0, stream>>>(bsum, row_ptr);
    scan3_kernel<<<SBLK, 1024, 0, stream>>>(row_ptr, cursor, bsum);
    scatter_kernel<<<(EE + 255) / 256, 256, 0, stream>>>(ei, ei + EE, ea, cursor, ssrc, sea);

    const uint2* kvp = (const uint2*)kvh;
    float2* Out2 = (float2*)Outb;

    // ---- layer 0 ----
    qkvs0_kernel<<<NN / QNPB, 512, 0, stream>>>(x, Wq0, bq0, Wk0, bk0, Wv0, bv0,
                                                Ws0, bs0, Qh, kvh, Outb);
    edge_attn_kernel<<<NN / 4, 256, 0, stream>>>(row_ptr, ssrc, sea, We0, Qh, kvp, Out2);

    // ---- layer 1 ----
    ftq_kernel<<<NN / QNPB, 512, 0, stream>>>(Wt0, bt0,
        WqL, bqL, WkL, bkL, WvL, bvL, WsL, bsL, Qh, kvh, Outb);
    edge_attn_kernel<<<NN / 4, 256, 0, stream>>>(row_ptr, ssrc, sea, WeL, Qh, kvp, Out2);

    // ---- layer 2 ----
    ftq_kernel<<<NN / QNPB, 512, 0, stream>>>(WtL, btL,
        WqL + EMB * HC, bqL + HC, WkL + EMB * HC, bkL + HC,
        WvL + EMB * HC, bvL + HC, WsL + EMB * HC, bsL + HC, Qh, kvh, Outb);
    edge_attn_kernel<<<NN / 4, 256, 0, stream>>>(row_ptr, ssrc, sea,
        WeL + EDIM * HC, Qh, kvp, Out2);

    // ---- fused final transform + register-weight MLP head ----
    head2_kernel<<<NN / QNPB, 512, 0, stream>>>(Outb, WtL + (size_t)HC * EMB, btL + EMB,
                                                W1, b1, W2, b2, W3, b3, out);
}

// Round 16
// 624.903 us; speedup vs baseline: 1.1521x; 1.0085x over previous
//
#include <hip/hip_runtime.h>

#define NN 50000
#define EE 800000
#define FIN 16
#define EDIM 4
#define EMB 32
#define NH 4
#define HC 128          // EMB*NH
#define NL 2
#define DENSE 128
#define QNPB 50         // nodes per qkvs/ftq/head block (50000 = 1000 * 50)
#define SBLK 49         // scan blocks: ceil(50000/1024)

// unpack two packed fp16 -> float2
__device__ __forceinline__ float2 h2f2(unsigned int u) {
    union { unsigned int u; _Float16 h[2]; } c; c.u = u;
    return make_float2((float)c.h[0], (float)c.h[1]);
}
__device__ __forceinline__ unsigned int pkh2(float a, float b) {
    union { unsigned int u; _Float16 h[2]; } c;
    c.h[0] = (_Float16)a; c.h[1] = (_Float16)b; return c.u;
}

// ---------------- CSR build ----------------
__global__ void hist_kernel(const int* __restrict__ dst, int* __restrict__ counts) {
    int e = blockIdx.x * blockDim.x + threadIdx.x;
    if (e < EE) atomicAdd(&counts[dst[e]], 1);
}

__global__ __launch_bounds__(1024) void scan1_kernel(const int* __restrict__ cursor,
                                                     int* __restrict__ row_ptr,
                                                     int* __restrict__ bsum) {
    __shared__ int wsum[16];
    __shared__ int wpre[17];
    int tid = threadIdx.x, lane = tid & 63, wid = tid >> 6;
    int i = blockIdx.x * 1024 + tid;
    int v = (i < NN) ? cursor[i] : 0;
    int incl = v;
    #pragma unroll
    for (int off = 1; off < 64; off <<= 1) {
        int t = __shfl_up(incl, off, 64);
        if (lane >= off) incl += t;
    }
    if (lane == 63) wsum[wid] = incl;
    __syncthreads();
    if (tid == 0) {
        int acc = 0;
        #pragma unroll
        for (int w = 0; w < 16; ++w) { wpre[w] = acc; acc += wsum[w]; }
        wpre[16] = acc;
    }
    __syncthreads();
    if (i < NN) row_ptr[i] = wpre[wid] + incl - v;
    if (tid == 0) bsum[blockIdx.x] = wpre[16];
}

// scan3 with scan2 folded in: every block re-scans the 49 block sums in its first wave
__global__ __launch_bounds__(1024) void scan3_kernel(int* __restrict__ row_ptr,
                                                     int* __restrict__ cursor,
                                                     const int* __restrict__ bsum) {
    __shared__ int boff_s;
    __shared__ int total_s;
    int tid = threadIdx.x;
    if (tid < 64) {
        int v = (tid < SBLK) ? bsum[tid] : 0;
        int incl = v;
        #pragma unroll
        for (int off = 1; off < 64; off <<= 1) {
            int u = __shfl_up(incl, off, 64);
            if (tid >= off) incl += u;
        }
        // exclusive prefix for this block index
        if (tid == (int)blockIdx.x) boff_s = incl - v;
        if (tid == 63) total_s = incl;
    }
    __syncthreads();
    int i = blockIdx.x * 1024 + tid;
    if (i < NN) {
        int r = row_ptr[i] + boff_s;
        row_ptr[i] = r;
        cursor[i] = r;
    }
    if (blockIdx.x == 0 && tid == 0) row_ptr[NN] = total_s;   // == EE
}

// edge record: x=src, y=ea fp16(0,1), z=ea fp16(2,3), w=unused — one 16B store
__global__ void scatter_kernel(const int* __restrict__ src, const int* __restrict__ dst,
                               const float* __restrict__ ea, int* __restrict__ cursor,
                               uint4* __restrict__ edges) {
    int e = blockIdx.x * blockDim.x + threadIdx.x;
    if (e >= EE) return;
    int d = dst[e];
    int pos = atomicAdd(&cursor[d], 1);
    float4 q = *reinterpret_cast<const float4*>(ea + (size_t)e * 4);
    uint4 rec;
    rec.x = (unsigned int)src[e];
    rec.y = pkh2(q.x, q.y);
    rec.z = pkh2(q.z, q.w);
    rec.w = 0u;
    edges[pos] = rec;
}

// ------- layer-0 projections: Q fp16, K/V packed fp16, skip into Out; f4 LDS --------
__global__ __launch_bounds__(512) void qkvs0_kernel(const float* __restrict__ x,
        const float* __restrict__ Wq, const float* __restrict__ bq,
        const float* __restrict__ Wk, const float* __restrict__ bk,
        const float* __restrict__ Wv, const float* __restrict__ bv,
        const float* __restrict__ Ws, const float* __restrict__ bs,
        _Float16* __restrict__ Qh, _Float16* __restrict__ kvh,
        float* __restrict__ Out) {
    __shared__ __align__(16) float hs[QNPB * FIN];
    int tid = threadIdx.x;
    int m = tid >> 7, c = tid & 127;
    const float* W; const float* b;
    switch (m) {
        case 0:  W = Wq; b = bq; break;
        case 1:  W = Wk; b = bk; break;
        case 2:  W = Wv; b = bv; break;
        default: W = Ws; b = bs; break;
    }
    float w[FIN];
    #pragma unroll
    for (int f = 0; f < FIN; ++f) w[f] = W[f * HC + c];
    float bias = b[c];
    int node0 = blockIdx.x * QNPB;
    {   // float4 staging copy
        const float4* src4 = (const float4*)(x + (size_t)node0 * FIN);
        float4* dst4 = (float4*)hs;
        for (int i = tid; i < QNPB * FIN / 4; i += 512) dst4[i] = src4[i];
    }
    __syncthreads();
    const float4* hs4 = (const float4*)hs;
    for (int k = 0; k < QNPB; ++k) {
        float s = bias;
        #pragma unroll
        for (int f4 = 0; f4 < FIN / 4; ++f4) {
            float4 hv = hs4[k * (FIN / 4) + f4];
            s += hv.x * w[4 * f4] + hv.y * w[4 * f4 + 1]
               + hv.z * w[4 * f4 + 2] + hv.w * w[4 * f4 + 3];
        }
        size_t n = node0 + k;
        if      (m == 0) Qh[n * HC + c] = (_Float16)s;
        else if (m == 1) kvh[n * 256 + 2 * c] = (_Float16)s;
        else if (m == 2) kvh[n * 256 + 2 * c + 1] = (_Float16)s;
        else             Out[n * HC + c] = s;
    }
}

// ---- fused transform + projections, register-cached Wt (round-11 stage T) ----------
__global__ __launch_bounds__(512) void ftq_kernel(const float* __restrict__ Wt,
        const float* __restrict__ bt,
        const float* __restrict__ Wq, const float* __restrict__ bq,
        const float* __restrict__ Wk, const float* __restrict__ bk,
        const float* __restrict__ Wv, const float* __restrict__ bv,
        const float* __restrict__ Ws, const float* __restrict__ bs,
        _Float16* __restrict__ Qh, _Float16* __restrict__ kvh,
        float* __restrict__ Out) {
    __shared__ __align__(16) float os[QNPB * HC];   // 25.6 KB
    __shared__ __align__(16) float hs[QNPB * EMB];  // 6.4 KB
    int tid = threadIdx.x;
    int node0 = blockIdx.x * QNPB;
    int g = tid >> 7;                   // 4 node-groups (2 waves each)

    {   // float4 staging copy
        const float4* src4 = (const float4*)(Out + (size_t)node0 * HC);
        float4* dst4 = (float4*)os;
        for (int i = tid; i < QNPB * HC / 4; i += 512) dst4[i] = src4[i];
    }

    // stage T: h = relu(bt + Out @ Wt). thread (g, cT=(tid&127)>>2, seg=tid&3)
    int cT = (tid & 127) >> 2, seg = tid & 3;
    float wt[32];
    #pragma unroll
    for (int j = 0; j < 32; ++j) wt[j] = Wt[(seg * 32 + j) * EMB + cT];
    float btc = bt[cT];
    __syncthreads();
    for (int k = g; k < QNPB; k += 4) {
        float p = 0.f;
        const float4* r4 = (const float4*)(os + k * HC + seg * 32);
        #pragma unroll
        for (int j4 = 0; j4 < 8; ++j4) {
            float4 rv = r4[j4];
            p += rv.x * wt[4 * j4] + rv.y * wt[4 * j4 + 1]
               + rv.z * wt[4 * j4 + 2] + rv.w * wt[4 * j4 + 3];
        }
        p += __shfl_xor(p, 1, 64);      // seg pairs
        p += __shfl_xor(p, 2, 64);
        if (seg == 0) hs[k * EMB + cT] = fmaxf(p + btc, 0.f);
    }
    __syncthreads();

    // stage QKVS: weights in registers (EMB=32/thread), float4 h reads
    int m = tid >> 7, c = tid & 127;
    const float* W; const float* b;
    switch (m) {
        case 0:  W = Wq; b = bq; break;
        case 1:  W = Wk; b = bk; break;
        case 2:  W = Wv; b = bv; break;
        default: W = Ws; b = bs; break;
    }
    float w[EMB];
    #pragma unroll
    for (int f = 0; f < EMB; ++f) w[f] = W[f * HC + c];
    float bias = b[c];
    const float4* hs4 = (const float4*)hs;
    for (int k = 0; k < QNPB; ++k) {
        float s = bias;
        #pragma unroll
        for (int f4 = 0; f4 < EMB / 4; ++f4) {
            float4 hv = hs4[k * (EMB / 4) + f4];
            s += hv.x * w[4 * f4] + hv.y * w[4 * f4 + 1]
               + hv.z * w[4 * f4 + 2] + hv.w * w[4 * f4 + 3];
        }
        size_t n = node0 + k;
        if      (m == 0) Qh[n * HC + c] = (_Float16)s;
        else if (m == 1) kvh[n * 256 + 2 * c] = (_Float16)s;
        else if (m == 2) kvh[n * 256 + 2 * c + 1] = (_Float16)s;
        else             Out[n * HC + c] = s;
    }
}

// ------- edge attention: fp16 Q + merged 16B edge record + fp16 KV gather ------------
__global__ __launch_bounds__(256) void edge_attn_kernel(const int* __restrict__ row_ptr,
        const uint4* __restrict__ edges,
        const float* __restrict__ We,
        const _Float16* __restrict__ Qh, const uint2* __restrict__ kvp,
        float2* __restrict__ Out) {
    int n = blockIdx.x * 4 + (threadIdx.x >> 6);   // grid*4 == NN exactly
    int lane = threadIdx.x & 63;
    int ch0 = 2 * lane, ch1 = 2 * lane + 1;
    float we0[4], we1[4];
    #pragma unroll
    for (int d = 0; d < 4; ++d) { we0[d] = We[d * HC + ch0]; we1[d] = We[d * HC + ch1]; }
    float2 q = h2f2(((const unsigned int*)Qh)[(size_t)n * 64 + lane]);
    int start = row_ptr[n], end = row_ptr[n + 1];
    float z = 0.f, acc0 = 0.f, acc1 = 0.f;
    const float SC = 0.17677669529663687f;  // 1/sqrt(32)
    int i = start;
    for (; i + 1 < end; i += 2) {
        uint4 rA = edges[i], rB = edges[i + 1];                  // wave-uniform 16B
        int sA = (int)rA.x, sB = (int)rB.x;
        sA = sA < 0 ? 0 : (sA >= NN ? NN - 1 : sA);
        sB = sB < 0 ? 0 : (sB >= NN ? NN - 1 : sB);
        uint2 kvA = kvp[(size_t)sA * 64 + lane];                 // k0,v0,k1,v1 fp16
        uint2 kvB = kvp[(size_t)sB * 64 + lane];
        float2 eAxy = h2f2(rA.y), eAzw = h2f2(rA.z);
        float2 eBxy = h2f2(rB.y), eBzw = h2f2(rB.z);
        float eA0 = eAxy.x * we0[0] + eAxy.y * we0[1] + eAzw.x * we0[2] + eAzw.y * we0[3];
        float eA1 = eAxy.x * we1[0] + eAxy.y * we1[1] + eAzw.x * we1[2] + eAzw.y * we1[3];
        float eB0 = eBxy.x * we0[0] + eBxy.y * we0[1] + eBzw.x * we0[2] + eBzw.y * we0[3];
        float eB1 = eBxy.x * we1[0] + eBxy.y * we1[1] + eBzw.x * we1[2] + eBzw.y * we1[3];
        float2 kvA0 = h2f2(kvA.x), kvA1 = h2f2(kvA.y);           // (k,v) ch0 / ch1
        float2 kvB0 = h2f2(kvB.x), kvB1 = h2f2(kvB.y);
        float pA = q.x * (kvA0.x + eA0) + q.y * (kvA1.x + eA1);
        float pB = q.x * (kvB0.x + eB0) + q.y * (kvB1.x + eB1);
        #pragma unroll
        for (int off = 1; off < 16; off <<= 1) {                 // 16-lane head groups
            pA += __shfl_xor(pA, off, 64);
            pB += __shfl_xor(pB, off, 64);
        }
        float xA = __expf(pA * SC), xB = __expf(pB * SC);
        z += xA + xB;
        acc0 += xA * (kvA0.y + eA0) + xB * (kvB0.y + eB0);
        acc1 += xA * (kvA1.y + eA1) + xB * (kvB1.y + eB1);
    }
    if (i < end) {
        uint4 r = edges[i];
        int s = (int)r.x;
        s = s < 0 ? 0 : (s >= NN ? NN - 1 : s);
        uint2 kv = kvp[(size_t)s * 64 + lane];
        float2 exy = h2f2(r.y), ezw = h2f2(r.z);
        float e0 = exy.x * we0[0] + exy.y * we0[1] + ezw.x * we0[2] + ezw.y * we0[3];
        float e1 = exy.x * we1[0] + exy.y * we1[1] + ezw.x * we1[2] + ezw.y * we1[3];
        float2 kv0 = h2f2(kv.x), kv1 = h2f2(kv.y);
        float p = q.x * (kv0.x + e0) + q.y * (kv1.x + e1);
        #pragma unroll
        for (int off = 1; off < 16; off <<= 1) p += __shfl_xor(p, off, 64);
        float x = __expf(p * SC);
        z += x;
        acc0 += x * (kv0.y + e0);
        acc1 += x * (kv1.y + e1);
    }
    float inv = 1.f / (z + 1e-16f);
    size_t oi = (size_t)n * 64 + lane;
    float2 o = Out[oi];
    o.x += acc0 * inv;
    o.y += acc1 * inv;
    Out[oi] = o;
}

// ---- fused final transform + MLP head, register weights (round-11 stage T) ----------
__global__ __launch_bounds__(512) void head2_kernel(const float* __restrict__ Outb,
        const float* __restrict__ Wt, const float* __restrict__ bt,
        const float* __restrict__ W1, const float* __restrict__ b1,
        const float* __restrict__ W2, const float* __restrict__ b2,
        const float* __restrict__ W3, const float* __restrict__ b3,
        float* __restrict__ out) {
    __shared__ __align__(16) float os[QNPB * HC];   // 25.6 KB; reused as d1s
    __shared__ __align__(16) float hs[QNPB * EMB];  // 6.4 KB
    __shared__ __align__(16) float d2s[QNPB * 64];  // 12.8 KB
    float* d1s = os;                     // alias: os dead once hs is built
    int tid = threadIdx.x;
    int node0 = blockIdx.x * QNPB;
    int g = tid >> 7;                    // 4 node-groups (2 waves each)

    {   // float4 staging copy
        const float4* src4 = (const float4*)(Outb + (size_t)node0 * HC);
        float4* dst4 = (float4*)os;
        for (int i = tid; i < QNPB * HC / 4; i += 512) dst4[i] = src4[i];
    }

    // stage T
    int cT = (tid & 127) >> 2, seg = tid & 3;
    float wt[32];
    #pragma unroll
    for (int j = 0; j < 32; ++j) wt[j] = Wt[(seg * 32 + j) * EMB + cT];
    float btc = bt[cT];
    __syncthreads();
    for (int k = g; k < QNPB; k += 4) {
        float p = 0.f;
        const float4* r4 = (const float4*)(os + k * HC + seg * 32);
        #pragma unroll
        for (int j4 = 0; j4 < 8; ++j4) {
            float4 rv = r4[j4];
            p += rv.x * wt[4 * j4] + rv.y * wt[4 * j4 + 1]
               + rv.z * wt[4 * j4 + 2] + rv.w * wt[4 * j4 + 3];
        }
        p += __shfl_xor(p, 1, 64);
        p += __shfl_xor(p, 2, 64);
        if (seg == 0) hs[k * EMB + cT] = fmaxf(p + btc, 0.f);
    }
    __syncthreads();

    // stage 1: d1 = relu(b1 + h @ W1)
    int c1 = tid & 127;
    float w1[32];
    #pragma unroll
    for (int f = 0; f < 32; ++f) w1[f] = W1[f * DENSE + c1];
    float b1c = b1[c1];
    const float4* hs4 = (const float4*)hs;
    for (int k = g; k < QNPB; k += 4) {
        float s = b1c;
        #pragma unroll
        for (int f4 = 0; f4 < 8; ++f4) {
            float4 hv = hs4[k * 8 + f4];
            s += hv.x * w1[4 * f4] + hv.y * w1[4 * f4 + 1]
               + hv.z * w1[4 * f4 + 2] + hv.w * w1[4 * f4 + 3];
        }
        d1s[k * DENSE + c1] = fmaxf(s, 0.f);
    }
    __syncthreads();

    // stage 2: d2 = relu(b2 + d1 @ W2)
    int c2 = (tid & 127) >> 1, hh = tid & 1;
    float w2[64];
    #pragma unroll
    for (int j = 0; j < 64; ++j) w2[j] = W2[(hh * 64 + j) * 64 + c2];
    float b2c = b2[c2];
    for (int k = g; k < QNPB; k += 4) {
        float p = 0.f;
        const float4* r4 = (const float4*)(d1s + k * DENSE + hh * 64);
        #pragma unroll
        for (int j4 = 0; j4 < 16; ++j4) {
            float4 rv = r4[j4];
            p += rv.x * w2[4 * j4] + rv.y * w2[4 * j4 + 1]
               + rv.z * w2[4 * j4 + 2] + rv.w * w2[4 * j4 + 3];
        }
        p += __shfl_xor(p, 1, 64);
        if (hh == 0) d2s[k * 64 + c2] = fmaxf(p + b2c, 0.f);
    }
    __syncthreads();

    // stage 3
    int w = tid >> 6, lane = tid & 63;
    float w3r = W3[lane];
    float b3r = b3[0];
    for (int k = w; k < QNPB; k += 8) {
        float t = d2s[k * 64 + lane] * w3r;
        #pragma unroll
        for (int off = 1; off < 64; off <<= 1) t += __shfl_xor(t, off, 64);
        if (lane == 0) out[node0 + k] = 1.f / (1.f + __expf(-(t + b3r)));
    }
}

extern "C" void kernel_launch(void* const* d_in, const int* in_sizes, int n_in,
                              void* d_out, int out_size, void* d_ws, size_t ws_size,
                              hipStream_t stream) {
    const float* x   = (const float*)d_in[0];
    const int*   ei  = (const int*)d_in[1];    // [2,E]: src=ei, dst=ei+E
    const float* ea  = (const float*)d_in[2];
    const float* Wq0 = (const float*)d_in[3];  const float* bq0 = (const float*)d_in[4];
    const float* Wk0 = (const float*)d_in[5];  const float* bk0 = (const float*)d_in[6];
    const float* Wv0 = (const float*)d_in[7];  const float* bv0 = (const float*)d_in[8];
    const float* We0 = (const float*)d_in[9];
    const float* Ws0 = (const float*)d_in[10]; const float* bs0 = (const float*)d_in[11];
    const float* Wt0 = (const float*)d_in[12]; const float* bt0 = (const float*)d_in[13];
    const float* WqL = (const float*)d_in[14]; const float* bqL = (const float*)d_in[15];
    const float* WkL = (const float*)d_in[16]; const float* bkL = (const float*)d_in[17];
    const float* WvL = (const float*)d_in[18]; const float* bvL = (const float*)d_in[19];
    const float* WeL = (const float*)d_in[20];
    const float* WsL = (const float*)d_in[21]; const float* bsL = (const float*)d_in[22];
    const float* WtL = (const float*)d_in[23]; const float* btL = (const float*)d_in[24];
    const float* W1  = (const float*)d_in[25]; const float* b1  = (const float*)d_in[26];
    const float* W2  = (const float*)d_in[27]; const float* b2  = (const float*)d_in[28];
    const float* W3  = (const float*)d_in[29]; const float* b3  = (const float*)d_in[30];
    float* out = (float*)d_out;

    char* ws = (char*)d_ws;
    size_t off = 0;
    auto alloc = [&](size_t bytes) -> void* {
        void* p = ws + off; off = (off + bytes + 255) & ~(size_t)255; return p;
    };
    int*      cursor  = (int*)     alloc((size_t)NN * 4);
    int*      row_ptr = (int*)     alloc((size_t)(NN + 1) * 4);
    int*      bsum    = (int*)     alloc((size_t)SBLK * 4);
    uint4*    edges   = (uint4*)   alloc((size_t)EE * 16);
    _Float16* Qh      = (_Float16*)alloc((size_t)NN * HC * 2);
    _Float16* kvh     = (_Float16*)alloc((size_t)NN * HC * 2 * 2);  // (k,v) interleaved
    float*    Outb    = (float*)   alloc((size_t)NN * HC * 4);
    // total ~77 MB

    // ---- CSR by dst (edge_index shared by all 3 conv layers) ----
    hipMemsetAsync(cursor, 0, (size_t)NN * 4, stream);
    hist_kernel<<<(EE + 255) / 256, 256, 0, stream>>>(ei + EE, cursor);
    scan1_kernel<<<SBLK, 1024, 0, stream>>>(cursor, row_ptr, bsum);
    scan3_kernel<<<SBLK, 1024, 0, stream>>>(row_ptr, cursor, bsum);   // scan2 folded in
    scatter_kernel<<<(EE + 255) / 256, 256, 0, stream>>>(ei, ei + EE, ea, cursor, edges);

    const uint2* kvp = (const uint2*)kvh;
    float2* Out2 = (float2*)Outb;

    // ---- layer 0 ----
    qkvs0_kernel<<<NN / QNPB, 512, 0, stream>>>(x, Wq0, bq0, Wk0, bk0, Wv0, bv0,
                                                Ws0, bs0, Qh, kvh, Outb);
    edge_attn_kernel<<<NN / 4, 256, 0, stream>>>(row_ptr, edges, We0, Qh, kvp, Out2);

    // ---- layer 1 ----
    ftq_kernel<<<NN / QNPB, 512, 0, stream>>>(Wt0, bt0,
        WqL, bqL, WkL, bkL, WvL, bvL, WsL, bsL, Qh, kvh, Outb);
    edge_attn_kernel<<<NN / 4, 256, 0, stream>>>(row_ptr, edges, WeL, Qh, kvp, Out2);

    // ---- layer 2 ----
    ftq_kernel<<<NN / QNPB, 512, 0, stream>>>(WtL, btL,
        WqL + EMB * HC, bqL + HC, WkL + EMB * HC, bkL + HC,
        WvL + EMB * HC, bvL + HC, WsL + EMB * HC, bsL + HC, Qh, kvh, Outb);
    edge_attn_kernel<<<NN / 4, 256, 0, stream>>>(row_ptr, edges,
        WeL + EDIM * HC, Qh, kvp, Out2);

    // ---- fused final transform + register-weight MLP head ----
    head2_kernel<<<NN / QNPB, 512, 0, stream>>>(Outb, WtL + (size_t)HC * EMB, btL + EMB,
                                                W1, b1, W2, b2, W3, b3, out);
}